// Round 18
// baseline (71.349 us; speedup 1.0000x reference)
//
#include <hip/hip_runtime.h>

#define Cc 256
#define Hh 96
#define Ww 128
#define CH_STRIDE (Hh * Ww)   // 12288 floats per channel plane
#define ROWS 16               // TH=8 output rows + 8 halo
#define SCOLS 24              // staged cols: w0-4 .. w0+19 (only band-used cols)
#define ACOLS 32              // addressed cols (t=1 n16>=8 reads hit cols 24..31 =
                              //  garbage, feeding only dj>8 outputs -> discarded)
#define CSL  40               // shorts per (row,col) cell: 80B stride (16B-aligned)
#define UNITS 3               // staging units/thread: 4*16*24 / 512

typedef __attribute__((ext_vector_type(8))) short bf16x8;  // 8 bf16 in 4 VGPRs
typedef __attribute__((ext_vector_type(4))) float f32x4;

static __device__ __forceinline__ unsigned cvt_pk(float lo, float hi) {
  unsigned r;
  asm("v_cvt_pk_bf16_f32 %0, %1, %2" : "=v"(r) : "v"(lo), "v"(hi));
  return r;  // D[15:0]=bf16(lo), D[31:16]=bf16(hi)
}

// x2 prefetch of chunk `cx` into named register set
#define PF_LOAD(pf, cx)                                               \
  do {                                                                \
    const size_t cb_ = (size_t)(cx) * 32 * CH_STRIDE;                 \
    _Pragma("unroll")                                                 \
    for (int s = 0; s < UNITS; ++s)                                   \
      _Pragma("unroll")                                               \
      for (int j = 0; j < 8; ++j)                                     \
        pf[s][j] = uok[s] ? uptr[s][cb_ + (size_t)j * CH_STRIDE] : 0.f; \
  } while (0)

#define LDS_WRITE(pf)                                                 \
  do {                                                                \
    _Pragma("unroll")                                                 \
    for (int s = 0; s < UNITS; ++s) {                                 \
      uint4 pk;                                                       \
      pk.x = cvt_pk(pf[s][0], pf[s][1]);                              \
      pk.y = cvt_pk(pf[s][2], pf[s][3]);                              \
      pk.z = cvt_pk(pf[s][4], pf[s][5]);                              \
      pk.w = cvt_pk(pf[s][6], pf[s][7]);                              \
      *(uint4*)(&x2s[uoff[s]]) = pk;                                  \
    }                                                                 \
  } while (0)

#define A_LOAD(pa, cx)                                                \
  do {                                                                \
    const float* pAc_ = pA + (size_t)(cx) * 32 * CH_STRIDE;           \
    _Pragma("unroll")                                                 \
    for (int j = 0; j < 8; ++j) pa[j] = pAc_[(size_t)j * CH_STRIDE];  \
  } while (0)

#define COMPUTE(af)                                                   \
  do {                                                                \
    _Pragma("unroll")                                                 \
    for (int di = 0; di < 9; ++di) {                                  \
      const int r_ = wv + di;                                         \
      _Pragma("unroll")                                               \
      for (int t = 0; t < 2; ++t) {                                   \
        const bf16x8 bf_ = *(const bf16x8*)(                          \
            &x2s[(r_ * ACOLS + 16 * t + n16) * CSL + kgrp * 8]);      \
        acc[di][t] = __builtin_amdgcn_mfma_f32_16x16x32_bf16(         \
            af, bf_, acc[di][t], 0, 0, 0);                            \
      }                                                               \
    }                                                                 \
  } while (0)

#define AFRAG(af, pa)                                                 \
  do {                                                                \
    union { unsigned u[4]; bf16x8 v; } ux_;                           \
    ux_.u[0] = cvt_pk(pa[0], pa[1]);                                  \
    ux_.u[1] = cvt_pk(pa[2], pa[3]);                                  \
    ux_.u[2] = cvt_pk(pa[4], pa[5]);                                  \
    ux_.u[3] = cvt_pk(pa[6], pa[7]);                                  \
    af = ux_.v;                                                       \
  } while (0)

// corr[m=w][n=w'] via mfma_f32_16x16x32_bf16 (layouts verified PASS r12/r13/r16):
//   A lane l: x1[m=l&15][k=8*(l>>4)+j];  B lane l: x2[k][n=l&15]
//   D lane l, reg q: row m=(l>>4)*4+q, col n=l&15
__global__ __launch_bounds__(512)
void corr_mfma(const float* __restrict__ x1, const float* __restrict__ x2,
               float* __restrict__ out) {
  __shared__ __align__(16) unsigned short x2s[ROWS * ACOLS * CSL];  // 40960 B

  const int tid  = threadIdx.x;
  const int bid  = blockIdx.x;
  // XCD-chunked swizzle (proven r9): 768 = 8 XCDs * 96 contiguous
  const int sbid = (bid & 7) * 96 + (bid >> 3);

  const int wt  = sbid & 7;          // w-tile
  const int hgb = sbid >> 3;         // b*12 + hg
  const int hg  = hgb % 12;
  const int b   = hgb / 12;
  const int h0  = hg * 8;
  const int w0  = wt * 16;

  const int wv   = tid >> 6;         // wave 0..7 -> h = h0+wv
  const int lane = tid & 63;
  const int n16  = lane & 15;
  const int kgrp = lane >> 4;
  const int h    = h0 + wv;

  // ---- staging unit geometry (3 uniform units/thread, all static) ----
  const float* uptr[UNITS];
  int  uoff[UNITS];
  bool uok[UNITS];
#pragma unroll
  for (int s = 0; s < UNITS; ++s) {
    const int u   = tid + 512 * s;       // 0..1535
    const int chg = u / 384;             // channel group 0..3 (8 ch each)
    const int rem = u - chg * 384;
    const int r   = rem / SCOLS;         // staged row 0..15
    const int c   = rem - r * SCOLS;     // staged col 0..23
    const int gh  = h0 - 4 + r;
    const int gw  = w0 - 4 + c;
    uok[s] = (gh >= 0) & (gh < Hh) & (gw >= 0) & (gw < Ww);
    const int ghc = uok[s] ? gh : 0;     // clamp addr; value zeroed via uok
    const int gwc = uok[s] ? gw : 0;
    uptr[s] = x2 + ((size_t)(b * Cc + chg * 8) * Hh + ghc) * Ww + gwc;
    uoff[s] = (r * ACOLS + c) * CSL + chg * 8;
  }

  // A element base: x1[b][kgrp*8 + j][h][w0 + n16]
  const float* pA = x1 + ((size_t)b * Cc * Hh + h) * Ww + (w0 + n16)
                       + (size_t)kgrp * 8 * CH_STRIDE;

  f32x4 acc[9][2];
#pragma unroll
  for (int di = 0; di < 9; ++di)
#pragma unroll
    for (int t = 0; t < 2; ++t) acc[di][t] = (f32x4){0.f, 0.f, 0.f, 0.f};

  // ---- prologue: 2-deep x2 prefetch + 1-deep A prefetch ----
  float pfE[UNITS][8], pfO[UNITS][8], pa[8];
  PF_LOAD(pfE, 0);
  PF_LOAD(pfO, 1);
  A_LOAD(pa, 0);

  for (int ci = 0; ci < 8; ci += 2) {
    // ---- even chunk ci (pfE) ----
    __syncthreads();                 // prev compute done; LDS reusable
    LDS_WRITE(pfE);                  // waits (FIFO vmcnt) only on pfE's loads
    bf16x8 af;
    AFRAG(af, pa);
    A_LOAD(pa, ci + 1);              // for odd body
    if (ci < 6) PF_LOAD(pfE, ci + 2);  // in flight ~2 chunk-periods
    __syncthreads();                 // LDS ready
    COMPUTE(af);

    // ---- odd chunk ci+1 (pfO) ----
    __syncthreads();
    LDS_WRITE(pfO);
    AFRAG(af, pa);
    if (ci < 6) A_LOAD(pa, ci + 2);
    if (ci < 5) PF_LOAD(pfO, ci + 3);
    __syncthreads();
    COMPUTE(af);
  }

  // ---- epilogue: extract 9-band, scale, predicated scattered stores ----
  const float scale = 1.0f / (float)Cc;
#pragma unroll
  for (int di = 0; di < 9; ++di) {
#pragma unroll
    for (int t = 0; t < 2; ++t) {
#pragma unroll
      for (int q = 0; q < 4; ++q) {
        const int m  = kgrp * 4 + q;         // output w-offset in tile
        const int dj = 16 * t + n16 - m;     // band position
        if (dj >= 0 && dj <= 8) {
          out[(((size_t)b * 81 + di * 9 + dj) * Hh + h) * Ww + (w0 + m)]
              = acc[di][t][q] * scale;
        }
      }
    }
  }
}

extern "C" void kernel_launch(void* const* d_in, const int* in_sizes, int n_in,
                              void* d_out, int out_size, void* d_ws, size_t ws_size,
                              hipStream_t stream) {
  const float* x1 = (const float*)d_in[0];
  const float* x2 = (const float*)d_in[1];
  float* out = (float*)d_out;
  // 8 b * 12 hgroups * 8 wt = 768 blocks * 8 waves
  corr_mfma<<<768, 512, 0, stream>>>(x1, x2, out);
}